// Round 1
// baseline (739.825 us; speedup 1.0000x reference)
//
#include <hip/hip_runtime.h>

typedef __attribute__((ext_vector_type(8))) short short8;
typedef __attribute__((ext_vector_type(4))) float f32x4;

#define LDA 72  // padded LDS row stride (elements): 64 + 8 -> conflict-free b128 reads

__device__ __forceinline__ unsigned short f2bf(float f) {
  unsigned int u = __builtin_bit_cast(unsigned int, f);
  u += 0x7fffu + ((u >> 16) & 1u);  // RNE
  return (unsigned short)(u >> 16);
}

// ---------------- fp32 -> bf16 weight conversion ----------------
__global__ __launch_bounds__(256) void cvt_bf16_kernel(const float* __restrict__ src,
                                                       unsigned short* __restrict__ dst,
                                                       int n4) {
  int i = blockIdx.x * 256 + threadIdx.x;
  if (i >= n4) return;
  float4 f = ((const float4*)src)[i];
  unsigned int lo = (unsigned int)f2bf(f.x) | ((unsigned int)f2bf(f.y) << 16);
  unsigned int hi = (unsigned int)f2bf(f.z) | ((unsigned int)f2bf(f.w) << 16);
  uint2 u; u.x = lo; u.y = hi;
  ((uint2*)dst)[i] = u;
}

// ---------------- GEMM1: emb = patches @ W_embed^T + b + pos ----------------
// M=8192 (bn*1024 + ph*32 + pw), N=256 (d), K=4096 (c*64 + kh*8 + kw)
// A[m][k] gathered from x on the fly (8-elem k-runs are contiguous in x).
__global__ __launch_bounds__(256) void gemm1_embed(
    const float* __restrict__ x, const unsigned short* __restrict__ Wb,
    const float* __restrict__ b_embed, const float* __restrict__ pos,
    float* __restrict__ emb) {
  __shared__ __align__(16) unsigned short As[64 * LDA];
  __shared__ __align__(16) unsigned short Bs[64 * LDA];
  const int nt = blockIdx.x, mt = blockIdx.y;  // x fastest: A-tile reuse across nt in L2
  const int m0 = mt * 64, n0 = nt * 64;
  const int t = threadIdx.x;
  const int wave = t >> 6, lane = t & 63;
  const int wm = wave >> 1, wn = wave & 1;
  const int lr = lane & 15, lq = lane >> 4;
  f32x4 acc[2][2];
#pragma unroll
  for (int i = 0; i < 2; i++)
#pragma unroll
    for (int j = 0; j < 2; j++) acc[i][j] = f32x4{0.f, 0.f, 0.f, 0.f};

  for (int kt = 0; kt < 64; ++kt) {
    const int k0 = kt * 64;
    // stage A (64x64, fp32 gather -> bf16), 512 runs of 8
#pragma unroll
    for (int rr = 0; rr < 2; ++rr) {
      int r = t + rr * 256;
      int m = r >> 3, krun = r & 7;
      int gm = m0 + m;
      int bn = gm >> 10, nn = gm & 1023;
      int ph = nn >> 5, pw = nn & 31;
      int k = k0 + krun * 8;
      int c = k >> 6, kh = (k >> 3) & 7;
      const float* src = x + ((size_t)((bn << 6) + c) << 16) +
                         (size_t)((ph << 3) + kh) * 256 + (pw << 3);
      float4 f0 = *(const float4*)src;
      float4 f1 = *(const float4*)(src + 4);
      short8 v;
      v[0] = (short)f2bf(f0.x); v[1] = (short)f2bf(f0.y);
      v[2] = (short)f2bf(f0.z); v[3] = (short)f2bf(f0.w);
      v[4] = (short)f2bf(f1.x); v[5] = (short)f2bf(f1.y);
      v[6] = (short)f2bf(f1.z); v[7] = (short)f2bf(f1.w);
      *(short8*)&As[m * LDA + krun * 8] = v;
    }
    // stage B (B^T rows = W_embed rows, already bf16)
#pragma unroll
    for (int rr = 0; rr < 2; ++rr) {
      int r = t + rr * 256;
      int n = r >> 3, krun = r & 7;
      *(short8*)&Bs[n * LDA + krun * 8] =
          *(const short8*)(Wb + (size_t)(n0 + n) * 4096 + k0 + krun * 8);
    }
    __syncthreads();
#pragma unroll
    for (int kc = 0; kc < 2; ++kc) {
      short8 a0 = *(const short8*)&As[(wm * 32 + lr) * LDA + kc * 32 + lq * 8];
      short8 a1 = *(const short8*)&As[(wm * 32 + 16 + lr) * LDA + kc * 32 + lq * 8];
      short8 b0 = *(const short8*)&Bs[(wn * 32 + lr) * LDA + kc * 32 + lq * 8];
      short8 b1 = *(const short8*)&Bs[(wn * 32 + 16 + lr) * LDA + kc * 32 + lq * 8];
      acc[0][0] = __builtin_amdgcn_mfma_f32_16x16x32_bf16(a0, b0, acc[0][0], 0, 0, 0);
      acc[0][1] = __builtin_amdgcn_mfma_f32_16x16x32_bf16(a0, b1, acc[0][1], 0, 0, 0);
      acc[1][0] = __builtin_amdgcn_mfma_f32_16x16x32_bf16(a1, b0, acc[1][0], 0, 0, 0);
      acc[1][1] = __builtin_amdgcn_mfma_f32_16x16x32_bf16(a1, b1, acc[1][1], 0, 0, 0);
    }
    __syncthreads();
  }
#pragma unroll
  for (int mi = 0; mi < 2; ++mi)
#pragma unroll
    for (int ni = 0; ni < 2; ++ni) {
      int col = n0 + wn * 32 + ni * 16 + lr;
      float be = b_embed[col];
      int rbase = m0 + wm * 32 + mi * 16 + lq * 4;
#pragma unroll
      for (int r2 = 0; r2 < 4; ++r2) {
        int row = rbase + r2;
        int n = row & 1023;
        emb[(size_t)row * 256 + col] = acc[mi][ni][r2] + be + pos[(size_t)n * 256 + col];
      }
    }
}

// ---------------- q: head-mean folded into Wq -> q[bn][h][n] ----------------
__global__ __launch_bounds__(256) void q_kernel(const float* __restrict__ emb,
                                                const float* __restrict__ Wq,
                                                float* __restrict__ q) {
  __shared__ float WqR[4 * 256];
  const int t = threadIdx.x;
  for (int idx = t; idx < 1024; idx += 256) {
    int h = idx >> 8, e = idx & 255;
    float s = 0.f;
    for (int j = 0; j < 64; ++j) s += Wq[(size_t)(h * 64 + j) * 256 + e];
    WqR[idx] = s * (1.f / 64.f);
  }
  __syncthreads();
  const int bn = blockIdx.x >> 2;
  const int n = ((blockIdx.x & 3) << 8) + t;
  const size_t row = (size_t)bn * 1024 + n;
  const float4* er = (const float4*)(emb + row * 256);
  const float4* w4 = (const float4*)WqR;
  float a0 = 0, a1 = 0, a2 = 0, a3 = 0;
  for (int j = 0; j < 64; ++j) {
    float4 ev = er[j];
    float4 w0 = w4[j], w1 = w4[64 + j], w2 = w4[128 + j], w3 = w4[192 + j];
    a0 += ev.x * w0.x + ev.y * w0.y + ev.z * w0.z + ev.w * w0.w;
    a1 += ev.x * w1.x + ev.y * w1.y + ev.z * w1.z + ev.w * w1.w;
    a2 += ev.x * w2.x + ev.y * w2.y + ev.z * w2.z + ev.w * w2.w;
    a3 += ev.x * w3.x + ev.y * w3.y + ev.z * w3.z + ev.w * w3.w;
  }
  q[(size_t)(bn * 4 + 0) * 1024 + n] = a0;
  q[(size_t)(bn * 4 + 1) * 1024 + n] = a1;
  q[(size_t)(bn * 4 + 2) * 1024 + n] = a2;
  q[(size_t)(bn * 4 + 3) * 1024 + n] = a3;
}

// ---------------- k = sigmoid(q @ Wk^T) -> kk[bn][h][m] ----------------
__global__ __launch_bounds__(256) void k_kernel(const float* __restrict__ q,
                                                const float* __restrict__ Wk,
                                                float* __restrict__ kk) {
  __shared__ float qs[1024];
  const int bh = blockIdx.x >> 2;
  const int mc = blockIdx.x & 3;
  const int t = threadIdx.x;
  for (int i = t; i < 1024; i += 256) qs[i] = q[(size_t)bh * 1024 + i];
  __syncthreads();
  const int m = mc * 256 + t;
  const float4* wr = (const float4*)(Wk + (size_t)m * 1024);
  const float4* q4 = (const float4*)qs;
  float s = 0.f;
  for (int j = 0; j < 256; ++j) {
    float4 w = wr[j], qq = q4[j];
    s += w.x * qq.x + w.y * qq.y + w.z * qq.z + w.w * qq.w;
  }
  kk[(size_t)bh * 1024 + m] = 1.f / (1.f + __expf(-s));
}

// ---------------- v = emb @ Wv^T; outv = gate * v (bf16) ----------------
__global__ __launch_bounds__(256) void vkv_kernel(const float* __restrict__ emb,
                                                  const float* __restrict__ Wv,
                                                  const float* __restrict__ kk,
                                                  unsigned short* __restrict__ outv) {
  __shared__ float es[256];
  const int n = blockIdx.x, bn = blockIdx.y;
  const size_t row = (size_t)bn * 1024 + n;
  const int t = threadIdx.x;
  es[t] = emb[row * 256 + t];
  __syncthreads();
  const float4* wr = (const float4*)(Wv + (size_t)t * 256);
  const float4* e4 = (const float4*)es;
  float s = 0.f;
  for (int j = 0; j < 64; ++j) {
    float4 w = wr[j], e = e4[j];
    s += w.x * e.x + w.y * e.y + w.z * e.z + w.w * e.w;
  }
  float g = kk[(size_t)(bn * 4 + (t >> 6)) * 1024 + n];
  outv[row * 256 + t] = f2bf(s * g);
}

// ---------------- GEMM2: out = outv @ Wout^T + b_out, folded to image ----------------
// M=8192, N=4096 (p = c*64+kh*8+kw), K=256
__global__ __launch_bounds__(256) void gemm2_out(
    const unsigned short* __restrict__ Abf, const unsigned short* __restrict__ Wob,
    const float* __restrict__ b_out, float* __restrict__ out) {
  __shared__ __align__(16) unsigned short As[64 * LDA];
  __shared__ __align__(16) unsigned short Bs[64 * LDA];
  const int nt = blockIdx.x, mt = blockIdx.y;
  const int m0 = mt * 64, n0 = nt * 64;
  const int t = threadIdx.x;
  const int wave = t >> 6, lane = t & 63;
  const int wm = wave >> 1, wn = wave & 1;
  const int lr = lane & 15, lq = lane >> 4;
  f32x4 acc[2][2];
#pragma unroll
  for (int i = 0; i < 2; i++)
#pragma unroll
    for (int j = 0; j < 2; j++) acc[i][j] = f32x4{0.f, 0.f, 0.f, 0.f};

  for (int kt = 0; kt < 4; ++kt) {
    const int k0 = kt * 64;
#pragma unroll
    for (int rr = 0; rr < 2; ++rr) {
      int r = t + rr * 256;
      int m = r >> 3, krun = r & 7;
      *(short8*)&As[m * LDA + krun * 8] =
          *(const short8*)(Abf + (size_t)(m0 + m) * 256 + k0 + krun * 8);
    }
#pragma unroll
    for (int rr = 0; rr < 2; ++rr) {
      int r = t + rr * 256;
      int n = r >> 3, krun = r & 7;
      *(short8*)&Bs[n * LDA + krun * 8] =
          *(const short8*)(Wob + (size_t)(n0 + n) * 256 + k0 + krun * 8);
    }
    __syncthreads();
#pragma unroll
    for (int kc = 0; kc < 2; ++kc) {
      short8 a0 = *(const short8*)&As[(wm * 32 + lr) * LDA + kc * 32 + lq * 8];
      short8 a1 = *(const short8*)&As[(wm * 32 + 16 + lr) * LDA + kc * 32 + lq * 8];
      short8 b0 = *(const short8*)&Bs[(wn * 32 + lr) * LDA + kc * 32 + lq * 8];
      short8 b1 = *(const short8*)&Bs[(wn * 32 + 16 + lr) * LDA + kc * 32 + lq * 8];
      acc[0][0] = __builtin_amdgcn_mfma_f32_16x16x32_bf16(a0, b0, acc[0][0], 0, 0, 0);
      acc[0][1] = __builtin_amdgcn_mfma_f32_16x16x32_bf16(a0, b1, acc[0][1], 0, 0, 0);
      acc[1][0] = __builtin_amdgcn_mfma_f32_16x16x32_bf16(a1, b0, acc[1][0], 0, 0, 0);
      acc[1][1] = __builtin_amdgcn_mfma_f32_16x16x32_bf16(a1, b1, acc[1][1], 0, 0, 0);
    }
    __syncthreads();
  }
#pragma unroll
  for (int mi = 0; mi < 2; ++mi)
#pragma unroll
    for (int ni = 0; ni < 2; ++ni) {
      int p = n0 + wn * 32 + ni * 16 + lr;
      int c = p >> 6, kh = (p >> 3) & 7, kw = p & 7;
      float bo = b_out[p];
      int rbase = m0 + wm * 32 + mi * 16 + lq * 4;
#pragma unroll
      for (int r2 = 0; r2 < 4; ++r2) {
        int row = rbase + r2;
        int bn = row >> 10, nn = row & 1023;
        int ph = nn >> 5, pw = nn & 31;
        size_t addr = ((size_t)((bn << 6) + c) << 16) +
                      (size_t)((ph << 3) + kh) * 256 + (pw << 3) + kw;
        out[addr] = acc[mi][ni][r2] + bo;
      }
    }
}

extern "C" void kernel_launch(void* const* d_in, const int* in_sizes, int n_in,
                              void* d_out, int out_size, void* d_ws, size_t ws_size,
                              hipStream_t stream) {
  const float* x       = (const float*)d_in[0];
  const float* W_embed = (const float*)d_in[1];
  const float* b_embed = (const float*)d_in[2];
  const float* pos     = (const float*)d_in[3];
  const float* Wq      = (const float*)d_in[4];
  const float* Wk      = (const float*)d_in[5];
  const float* Wv      = (const float*)d_in[6];
  const float* Wout    = (const float*)d_in[7];
  const float* b_out   = (const float*)d_in[8];
  float* out = (float*)d_out;

  char* ws = (char*)d_ws;
  float* emb          = (float*)(ws);                                  // 8 MiB
  float* q            = (float*)(ws + 8 * 1024 * 1024);                // 128 KiB
  float* kk           = (float*)(ws + 8 * 1024 * 1024 + 131072);       // 128 KiB
  unsigned short* ov  = (unsigned short*)(ws + 8 * 1024 * 1024 + 262144);   // 4 MiB
  unsigned short* Wb  = (unsigned short*)(ws + 12 * 1024 * 1024 + 262144);  // 2 MiB
  unsigned short* Wob = (unsigned short*)(ws + 14 * 1024 * 1024 + 262144);  // 2 MiB

  cvt_bf16_kernel<<<1024, 256, 0, stream>>>(W_embed, Wb, 262144);
  cvt_bf16_kernel<<<1024, 256, 0, stream>>>(Wout, Wob, 262144);
  gemm1_embed<<<dim3(4, 128), 256, 0, stream>>>(x, Wb, b_embed, pos, emb);
  q_kernel<<<32, 256, 0, stream>>>(emb, Wq, q);
  k_kernel<<<128, 256, 0, stream>>>(q, Wk, kk);
  vkv_kernel<<<dim3(1024, 8), 256, 0, stream>>>(emb, Wv, kk, ov);
  gemm2_out<<<dim3(64, 128), 256, 0, stream>>>(ov, Wob, b_out, out);
}

// Round 2
// 389.338 us; speedup vs baseline: 1.9002x; 1.9002x over previous
//
#include <hip/hip_runtime.h>

typedef __attribute__((ext_vector_type(8))) short short8;
typedef __attribute__((ext_vector_type(4))) float f32x4;

#define LDA 72   // padded LDS row stride for bf16 GEMM tiles
#define QST 264  // q_kernel LDS stride (ushorts)
#define KST 257  // k_kernel LDS stride (floats)

__device__ __forceinline__ unsigned short f2bf(float f) {
  unsigned int u = __builtin_bit_cast(unsigned int, f);
  u += 0x7fffu + ((u >> 16) & 1u);  // RNE
  return (unsigned short)(u >> 16);
}
__device__ __forceinline__ float bf2f(unsigned short us) {
  return __builtin_bit_cast(float, (unsigned int)us << 16);
}

// ---------------- fp32 -> bf16 weight conversion ----------------
__global__ __launch_bounds__(256) void cvt_bf16_kernel(const float* __restrict__ src,
                                                       unsigned short* __restrict__ dst,
                                                       int n4) {
  int i = blockIdx.x * 256 + threadIdx.x;
  if (i >= n4) return;
  float4 f = ((const float4*)src)[i];
  unsigned int lo = (unsigned int)f2bf(f.x) | ((unsigned int)f2bf(f.y) << 16);
  unsigned int hi = (unsigned int)f2bf(f.z) | ((unsigned int)f2bf(f.w) << 16);
  uint2 u; u.x = lo; u.y = hi;
  ((uint2*)dst)[i] = u;
}

// ---------------- WqR[h][e] = mean_j Wq[h*64+j][e] ----------------
__global__ __launch_bounds__(256) void wqr_kernel(const float* __restrict__ Wq,
                                                  float* __restrict__ WqR) {
  int idx = blockIdx.x * 256 + threadIdx.x;  // 0..1023
  int h = idx >> 8, e = idx & 255;
  float s = 0.f;
  for (int j = 0; j < 64; ++j) s += Wq[(size_t)(h * 64 + j) * 256 + e];
  WqR[idx] = s * (1.f / 64.f);
}

// ---------------- GEMM1: emb_bf = bf16(patches @ W_embed^T + b + pos) ----------------
// M=8192, N=256, K=4096. Tile 64x128, grid (2,128).
__global__ __launch_bounds__(256) void gemm1_embed(
    const float* __restrict__ x, const unsigned short* __restrict__ Wb,
    const float* __restrict__ b_embed, const float* __restrict__ pos,
    unsigned short* __restrict__ emb_bf) {
  __shared__ __align__(16) unsigned short As[64 * LDA];
  __shared__ __align__(16) unsigned short Bs[128 * LDA];
  const int nt = blockIdx.x, mt = blockIdx.y;
  const int m0 = mt * 64, n0 = nt * 128;
  const int t = threadIdx.x;
  const int wave = t >> 6, lane = t & 63;
  const int wm = wave >> 1, wn = wave & 1;
  const int lr = lane & 15, lq = lane >> 4;
  f32x4 acc[2][4];
#pragma unroll
  for (int i = 0; i < 2; i++)
#pragma unroll
    for (int j = 0; j < 4; j++) acc[i][j] = f32x4{0.f, 0.f, 0.f, 0.f};

  for (int kt = 0; kt < 64; ++kt) {
    const int k0 = kt * 64;
    // stage A (64x64 fp32 gather -> bf16): 512 runs of 8, 2/thread
#pragma unroll
    for (int rr = 0; rr < 2; ++rr) {
      int r = t + rr * 256;
      int m = r >> 3, krun = r & 7;
      int gm = m0 + m;
      int bn = gm >> 10, nn = gm & 1023;
      int ph = nn >> 5, pw = nn & 31;
      int k = k0 + krun * 8;
      int c = k >> 6, kh = (k >> 3) & 7;
      const float* src = x + ((size_t)((bn << 6) + c) << 16) +
                         (size_t)((ph << 3) + kh) * 256 + (pw << 3);
      float4 f0 = *(const float4*)src;
      float4 f1 = *(const float4*)(src + 4);
      short8 v;
      v[0] = (short)f2bf(f0.x); v[1] = (short)f2bf(f0.y);
      v[2] = (short)f2bf(f0.z); v[3] = (short)f2bf(f0.w);
      v[4] = (short)f2bf(f1.x); v[5] = (short)f2bf(f1.y);
      v[6] = (short)f2bf(f1.z); v[7] = (short)f2bf(f1.w);
      *(short8*)&As[m * LDA + krun * 8] = v;
    }
    // stage B (128 rows of W_embed, bf16): 1024 runs, 4/thread
#pragma unroll
    for (int rr = 0; rr < 4; ++rr) {
      int r = t + rr * 256;
      int n = r >> 3, krun = r & 7;
      *(short8*)&Bs[n * LDA + krun * 8] =
          *(const short8*)(Wb + (size_t)(n0 + n) * 4096 + k0 + krun * 8);
    }
    __syncthreads();
#pragma unroll
    for (int kc = 0; kc < 2; ++kc) {
      short8 a0 = *(const short8*)&As[(wm * 32 + lr) * LDA + kc * 32 + lq * 8];
      short8 a1 = *(const short8*)&As[(wm * 32 + 16 + lr) * LDA + kc * 32 + lq * 8];
#pragma unroll
      for (int ni = 0; ni < 4; ++ni) {
        short8 b = *(const short8*)&Bs[(wn * 64 + ni * 16 + lr) * LDA + kc * 32 + lq * 8];
        acc[0][ni] = __builtin_amdgcn_mfma_f32_16x16x32_bf16(a0, b, acc[0][ni], 0, 0, 0);
        acc[1][ni] = __builtin_amdgcn_mfma_f32_16x16x32_bf16(a1, b, acc[1][ni], 0, 0, 0);
      }
    }
    __syncthreads();
  }
#pragma unroll
  for (int mi = 0; mi < 2; ++mi)
#pragma unroll
    for (int ni = 0; ni < 4; ++ni) {
      int col = n0 + wn * 64 + ni * 16 + lr;
      float be = b_embed[col];
      int rbase = m0 + wm * 32 + mi * 16 + lq * 4;
#pragma unroll
      for (int r2 = 0; r2 < 4; ++r2) {
        int row = rbase + r2;
        int n = row & 1023;
        emb_bf[(size_t)row * 256 + col] =
            f2bf(acc[mi][ni][r2] + be + pos[(size_t)n * 256 + col]);
      }
    }
}

// ---------------- q[bh][n] = emb_bf[row] . WqR[h] ----------------
// block: 64 rows, 256 threads (4 heads per row). grid 128.
__global__ __launch_bounds__(256) void q_kernel(const unsigned short* __restrict__ emb_bf,
                                                const float* __restrict__ WqR,
                                                float* __restrict__ q) {
  __shared__ __align__(16) unsigned short es[64 * QST];
  __shared__ float wq[1024];
  const int t = threadIdx.x;
  for (int i = t; i < 1024; i += 256) wq[i] = WqR[i];
  const int row0 = blockIdx.x * 64;
#pragma unroll
  for (int i = 0; i < 8; ++i) {
    int r = t + i * 256;  // 0..2047
    int rr = r >> 5, c8 = r & 31;
    *(short8*)&es[rr * QST + c8 * 8] =
        *(const short8*)(emb_bf + (size_t)(row0 + rr) * 256 + c8 * 8);
  }
  __syncthreads();
  const int row = t >> 2, h = t & 3;
  const float* w = wq + h * 256;
  float s = 0.f;
#pragma unroll 4
  for (int e8 = 0; e8 < 32; ++e8) {
    short8 v = *(const short8*)&es[row * QST + e8 * 8];
#pragma unroll
    for (int j = 0; j < 8; ++j)
      s += bf2f((unsigned short)v[j]) * w[e8 * 8 + j];
  }
  int grow = row0 + row;
  int bn = grow >> 10, n = grow & 1023;
  q[(size_t)(bn * 4 + h) * 1024 + n] = s;
}

// ---------------- kk[bh][m] = sigmoid(q[bh] . Wk[m]) ----------------
// grid 32 (m-chunks of 32). LDS-staged, coalesced.
__global__ __launch_bounds__(256) void k_kernel(const float* __restrict__ q,
                                                const float* __restrict__ Wk,
                                                float* __restrict__ kk) {
  __shared__ float wks[32 * KST];
  __shared__ float qs[32 * KST];
  const int m0 = blockIdx.x * 32;
  const int t = threadIdx.x;
  const int m = t & 31, bh4 = t >> 5;
  float acc[4] = {0.f, 0.f, 0.f, 0.f};
  for (int kt = 0; kt < 4; ++kt) {
    const int k0 = kt * 256;
#pragma unroll
    for (int i = 0; i < 32; ++i) {
      int r = t + i * 256;
      int rr = r >> 8, c = r & 255;
      wks[rr * KST + c] = Wk[(size_t)(m0 + rr) * 1024 + k0 + c];
      qs[rr * KST + c] = q[(size_t)rr * 1024 + k0 + c];
    }
    __syncthreads();
    for (int k = 0; k < 256; ++k) {
      float a = wks[m * KST + k];
      acc[0] += a * qs[(bh4 * 4 + 0) * KST + k];
      acc[1] += a * qs[(bh4 * 4 + 1) * KST + k];
      acc[2] += a * qs[(bh4 * 4 + 2) * KST + k];
      acc[3] += a * qs[(bh4 * 4 + 3) * KST + k];
    }
    __syncthreads();
  }
#pragma unroll
  for (int j = 0; j < 4; ++j)
    kk[(size_t)(bh4 * 4 + j) * 1024 + m0 + m] = 1.f / (1.f + __expf(-acc[j]));
}

// ---------------- vgemm: ov = bf16( (emb_bf @ Wv^T) * gate ) ----------------
// M=8192, N=256, K=256. Tile 64x64, grid (4,128).
__global__ __launch_bounds__(256) void vgemm_kernel(
    const unsigned short* __restrict__ Abf, const unsigned short* __restrict__ Wvb,
    const float* __restrict__ kk, unsigned short* __restrict__ ov) {
  __shared__ __align__(16) unsigned short As[64 * LDA];
  __shared__ __align__(16) unsigned short Bs[64 * LDA];
  const int nt = blockIdx.x, mt = blockIdx.y;
  const int m0 = mt * 64, n0 = nt * 64;
  const int t = threadIdx.x;
  const int wave = t >> 6, lane = t & 63;
  const int wm = wave >> 1, wn = wave & 1;
  const int lr = lane & 15, lq = lane >> 4;
  f32x4 acc[2][2];
#pragma unroll
  for (int i = 0; i < 2; i++)
#pragma unroll
    for (int j = 0; j < 2; j++) acc[i][j] = f32x4{0.f, 0.f, 0.f, 0.f};

  for (int kt = 0; kt < 4; ++kt) {
    const int k0 = kt * 64;
#pragma unroll
    for (int rr = 0; rr < 2; ++rr) {
      int r = t + rr * 256;
      int m = r >> 3, krun = r & 7;
      *(short8*)&As[m * LDA + krun * 8] =
          *(const short8*)(Abf + (size_t)(m0 + m) * 256 + k0 + krun * 8);
    }
#pragma unroll
    for (int rr = 0; rr < 2; ++rr) {
      int r = t + rr * 256;
      int n = r >> 3, krun = r & 7;
      *(short8*)&Bs[n * LDA + krun * 8] =
          *(const short8*)(Wvb + (size_t)(n0 + n) * 256 + k0 + krun * 8);
    }
    __syncthreads();
#pragma unroll
    for (int kc = 0; kc < 2; ++kc) {
      short8 a0 = *(const short8*)&As[(wm * 32 + lr) * LDA + kc * 32 + lq * 8];
      short8 a1 = *(const short8*)&As[(wm * 32 + 16 + lr) * LDA + kc * 32 + lq * 8];
      short8 b0 = *(const short8*)&Bs[(wn * 32 + lr) * LDA + kc * 32 + lq * 8];
      short8 b1 = *(const short8*)&Bs[(wn * 32 + 16 + lr) * LDA + kc * 32 + lq * 8];
      acc[0][0] = __builtin_amdgcn_mfma_f32_16x16x32_bf16(a0, b0, acc[0][0], 0, 0, 0);
      acc[0][1] = __builtin_amdgcn_mfma_f32_16x16x32_bf16(a0, b1, acc[0][1], 0, 0, 0);
      acc[1][0] = __builtin_amdgcn_mfma_f32_16x16x32_bf16(a1, b0, acc[1][0], 0, 0, 0);
      acc[1][1] = __builtin_amdgcn_mfma_f32_16x16x32_bf16(a1, b1, acc[1][1], 0, 0, 0);
    }
    __syncthreads();
  }
#pragma unroll
  for (int mi = 0; mi < 2; ++mi)
#pragma unroll
    for (int ni = 0; ni < 2; ++ni) {
      int col = n0 + wn * 32 + ni * 16 + lr;
      int h = col >> 6;
      int rbase = m0 + wm * 32 + mi * 16 + lq * 4;
#pragma unroll
      for (int r2 = 0; r2 < 4; ++r2) {
        int row = rbase + r2;
        int bn = row >> 10, n = row & 1023;
        float g = kk[(size_t)(bn * 4 + h) * 1024 + n];
        ov[(size_t)row * 256 + col] = f2bf(acc[mi][ni][r2] * g);
      }
    }
}

// ---------------- GEMM2: out = ov @ Wout^T + b_out, folded to image ----------------
// M=8192, N=4096, K=256. Tile 64x64, grid (64,128).
__global__ __launch_bounds__(256) void gemm2_out(
    const unsigned short* __restrict__ Abf, const unsigned short* __restrict__ Wob,
    const float* __restrict__ b_out, float* __restrict__ out) {
  __shared__ __align__(16) unsigned short As[64 * LDA];
  __shared__ __align__(16) unsigned short Bs[64 * LDA];
  const int nt = blockIdx.x, mt = blockIdx.y;
  const int m0 = mt * 64, n0 = nt * 64;
  const int t = threadIdx.x;
  const int wave = t >> 6, lane = t & 63;
  const int wm = wave >> 1, wn = wave & 1;
  const int lr = lane & 15, lq = lane >> 4;
  f32x4 acc[2][2];
#pragma unroll
  for (int i = 0; i < 2; i++)
#pragma unroll
    for (int j = 0; j < 2; j++) acc[i][j] = f32x4{0.f, 0.f, 0.f, 0.f};

  for (int kt = 0; kt < 4; ++kt) {
    const int k0 = kt * 64;
#pragma unroll
    for (int rr = 0; rr < 2; ++rr) {
      int r = t + rr * 256;
      int m = r >> 3, krun = r & 7;
      *(short8*)&As[m * LDA + krun * 8] =
          *(const short8*)(Abf + (size_t)(m0 + m) * 256 + k0 + krun * 8);
    }
#pragma unroll
    for (int rr = 0; rr < 2; ++rr) {
      int r = t + rr * 256;
      int n = r >> 3, krun = r & 7;
      *(short8*)&Bs[n * LDA + krun * 8] =
          *(const short8*)(Wob + (size_t)(n0 + n) * 256 + k0 + krun * 8);
    }
    __syncthreads();
#pragma unroll
    for (int kc = 0; kc < 2; ++kc) {
      short8 a0 = *(const short8*)&As[(wm * 32 + lr) * LDA + kc * 32 + lq * 8];
      short8 a1 = *(const short8*)&As[(wm * 32 + 16 + lr) * LDA + kc * 32 + lq * 8];
      short8 b0 = *(const short8*)&Bs[(wn * 32 + lr) * LDA + kc * 32 + lq * 8];
      short8 b1 = *(const short8*)&Bs[(wn * 32 + 16 + lr) * LDA + kc * 32 + lq * 8];
      acc[0][0] = __builtin_amdgcn_mfma_f32_16x16x32_bf16(a0, b0, acc[0][0], 0, 0, 0);
      acc[0][1] = __builtin_amdgcn_mfma_f32_16x16x32_bf16(a0, b1, acc[0][1], 0, 0, 0);
      acc[1][0] = __builtin_amdgcn_mfma_f32_16x16x32_bf16(a1, b0, acc[1][0], 0, 0, 0);
      acc[1][1] = __builtin_amdgcn_mfma_f32_16x16x32_bf16(a1, b1, acc[1][1], 0, 0, 0);
    }
    __syncthreads();
  }
#pragma unroll
  for (int mi = 0; mi < 2; ++mi)
#pragma unroll
    for (int ni = 0; ni < 2; ++ni) {
      int p = n0 + wn * 32 + ni * 16 + lr;
      int c = p >> 6, kh = (p >> 3) & 7, kw = p & 7;
      float bo = b_out[p];
      int rbase = m0 + wm * 32 + mi * 16 + lq * 4;
#pragma unroll
      for (int r2 = 0; r2 < 4; ++r2) {
        int row = rbase + r2;
        int bn = row >> 10, nn = row & 1023;
        int ph = nn >> 5, pw = nn & 31;
        size_t addr = ((size_t)((bn << 6) + c) << 16) +
                      (size_t)((ph << 3) + kh) * 256 + (pw << 3) + kw;
        out[addr] = acc[mi][ni][r2] + bo;
      }
    }
}

extern "C" void kernel_launch(void* const* d_in, const int* in_sizes, int n_in,
                              void* d_out, int out_size, void* d_ws, size_t ws_size,
                              hipStream_t stream) {
  const float* x       = (const float*)d_in[0];
  const float* W_embed = (const float*)d_in[1];
  const float* b_embed = (const float*)d_in[2];
  const float* pos     = (const float*)d_in[3];
  const float* Wq      = (const float*)d_in[4];
  const float* Wk      = (const float*)d_in[5];
  const float* Wv      = (const float*)d_in[6];
  const float* Wout    = (const float*)d_in[7];
  const float* b_out   = (const float*)d_in[8];
  float* out = (float*)d_out;

  char* ws = (char*)d_ws;
  const size_t MB = 1024 * 1024;
  unsigned short* emb_bf = (unsigned short*)(ws);                 // 4 MiB
  unsigned short* ov     = (unsigned short*)(ws + 4 * MB);        // 4 MiB
  unsigned short* Wb     = (unsigned short*)(ws + 8 * MB);        // 2 MiB
  unsigned short* Wob    = (unsigned short*)(ws + 10 * MB);       // 2 MiB
  unsigned short* Wvb    = (unsigned short*)(ws + 12 * MB);       // 128 KiB
  float* q               = (float*)(ws + 12 * MB + 131072);       // 128 KiB
  float* kk              = (float*)(ws + 12 * MB + 262144);       // 128 KiB
  float* WqR             = (float*)(ws + 12 * MB + 393216);       // 4 KiB

  cvt_bf16_kernel<<<1024, 256, 0, stream>>>(W_embed, Wb, 262144);
  cvt_bf16_kernel<<<1024, 256, 0, stream>>>(Wout, Wob, 262144);
  cvt_bf16_kernel<<<64, 256, 0, stream>>>(Wv, Wvb, 16384);
  wqr_kernel<<<4, 256, 0, stream>>>(Wq, WqR);
  gemm1_embed<<<dim3(2, 128), 256, 0, stream>>>(x, Wb, b_embed, pos, emb_bf);
  q_kernel<<<128, 256, 0, stream>>>(emb_bf, WqR, q);
  k_kernel<<<32, 256, 0, stream>>>(q, Wk, kk);
  vgemm_kernel<<<dim3(4, 128), 256, 0, stream>>>(emb_bf, Wvb, kk, ov);
  gemm2_out<<<dim3(64, 128), 256, 0, stream>>>(ov, Wob, b_out, out);
}

// Round 3
// 357.366 us; speedup vs baseline: 2.0702x; 1.0895x over previous
//
#include <hip/hip_runtime.h>

typedef __attribute__((ext_vector_type(8))) short short8;
typedef __attribute__((ext_vector_type(4))) float f32x4;

#define LDA 72   // padded LDS row stride for bf16 GEMM tiles (elements)
#define KST 260  // k_kernel LDS stride (floats, 16B-aligned rows, +4-bank rotation)

__device__ __forceinline__ unsigned short f2bf(float f) {
  unsigned int u = __builtin_bit_cast(unsigned int, f);
  u += 0x7fffu + ((u >> 16) & 1u);  // RNE
  return (unsigned short)(u >> 16);
}
__device__ __forceinline__ float bf2f(unsigned short us) {
  return __builtin_bit_cast(float, (unsigned int)us << 16);
}

// ---------------- prep: all weight conversions in one launch ----------------
__device__ __forceinline__ void cvt_block(const float* __restrict__ src,
                                          unsigned short* __restrict__ dst, int b) {
  int i = b * 256 + threadIdx.x;
  float4 f = ((const float4*)src)[i];
  unsigned int lo = (unsigned int)f2bf(f.x) | ((unsigned int)f2bf(f.y) << 16);
  unsigned int hi = (unsigned int)f2bf(f.z) | ((unsigned int)f2bf(f.w) << 16);
  uint2 u; u.x = lo; u.y = hi;
  ((uint2*)dst)[i] = u;
}

__global__ __launch_bounds__(256) void prep_kernel(
    const float* __restrict__ W_embed, const float* __restrict__ Wout,
    const float* __restrict__ Wv, const float* __restrict__ Wq,
    unsigned short* __restrict__ Wb, unsigned short* __restrict__ Wob,
    unsigned short* __restrict__ Wvb, float* __restrict__ WqR) {
  int b = blockIdx.x;
  if (b < 1024) { cvt_block(W_embed, Wb, b); return; }
  if (b < 2048) { cvt_block(Wout, Wob, b - 1024); return; }
  if (b < 2112) { cvt_block(Wv, Wvb, b - 2048); return; }
  // WqR[h][e] = mean_j Wq[h*64+j][e]
  int idx = (b - 2112) * 256 + threadIdx.x;  // 0..1023
  int h = idx >> 8, e = idx & 255;
  float s = 0.f;
  for (int j = 0; j < 64; ++j) s += Wq[(size_t)(h * 64 + j) * 256 + e];
  WqR[idx] = s * (1.f / 64.f);
}

// ---------------- GEMM1 (split-K): part[s] = patches @ W_embed^T (K-chunk s) ----------------
// M=8192, N=256, K=4096 split 4x1024. Tile 64x128, grid (2,128,4).
__global__ __launch_bounds__(256) void gemm1_embed(
    const float* __restrict__ x, const unsigned short* __restrict__ Wb,
    float* __restrict__ part) {
  __shared__ __align__(16) unsigned short As[64 * LDA];
  __shared__ __align__(16) unsigned short Bs[128 * LDA];
  const int nt = blockIdx.x, mt = blockIdx.y, sk = blockIdx.z;
  const int m0 = mt * 64, n0 = nt * 128;
  const int t = threadIdx.x;
  const int wave = t >> 6, lane = t & 63;
  const int wm = wave >> 1, wn = wave & 1;
  const int lr = lane & 15, lq = lane >> 4;
  f32x4 acc[2][4];
#pragma unroll
  for (int i = 0; i < 2; i++)
#pragma unroll
    for (int j = 0; j < 4; j++) acc[i][j] = f32x4{0.f, 0.f, 0.f, 0.f};

  for (int kt = sk * 16; kt < sk * 16 + 16; ++kt) {
    const int k0 = kt * 64;
#pragma unroll
    for (int rr = 0; rr < 2; ++rr) {
      int r = t + rr * 256;
      int m = r >> 3, krun = r & 7;
      int gm = m0 + m;
      int bn = gm >> 10, nn = gm & 1023;
      int ph = nn >> 5, pw = nn & 31;
      int k = k0 + krun * 8;
      int c = k >> 6, kh = (k >> 3) & 7;
      const float* src = x + ((size_t)((bn << 6) + c) << 16) +
                         (size_t)((ph << 3) + kh) * 256 + (pw << 3);
      float4 f0 = *(const float4*)src;
      float4 f1 = *(const float4*)(src + 4);
      short8 v;
      v[0] = (short)f2bf(f0.x); v[1] = (short)f2bf(f0.y);
      v[2] = (short)f2bf(f0.z); v[3] = (short)f2bf(f0.w);
      v[4] = (short)f2bf(f1.x); v[5] = (short)f2bf(f1.y);
      v[6] = (short)f2bf(f1.z); v[7] = (short)f2bf(f1.w);
      *(short8*)&As[m * LDA + krun * 8] = v;
    }
#pragma unroll
    for (int rr = 0; rr < 4; ++rr) {
      int r = t + rr * 256;
      int n = r >> 3, krun = r & 7;
      *(short8*)&Bs[n * LDA + krun * 8] =
          *(const short8*)(Wb + (size_t)(n0 + n) * 4096 + k0 + krun * 8);
    }
    __syncthreads();
#pragma unroll
    for (int kc = 0; kc < 2; ++kc) {
      short8 a0 = *(const short8*)&As[(wm * 32 + lr) * LDA + kc * 32 + lq * 8];
      short8 a1 = *(const short8*)&As[(wm * 32 + 16 + lr) * LDA + kc * 32 + lq * 8];
#pragma unroll
      for (int ni = 0; ni < 4; ++ni) {
        short8 b = *(const short8*)&Bs[(wn * 64 + ni * 16 + lr) * LDA + kc * 32 + lq * 8];
        acc[0][ni] = __builtin_amdgcn_mfma_f32_16x16x32_bf16(a0, b, acc[0][ni], 0, 0, 0);
        acc[1][ni] = __builtin_amdgcn_mfma_f32_16x16x32_bf16(a1, b, acc[1][ni], 0, 0, 0);
      }
    }
    __syncthreads();
  }
  float* pdst = part + (size_t)sk * 2097152;
#pragma unroll
  for (int mi = 0; mi < 2; ++mi)
#pragma unroll
    for (int ni = 0; ni < 4; ++ni) {
      int col = n0 + wn * 64 + ni * 16 + lr;
      int rbase = m0 + wm * 32 + mi * 16 + lq * 4;
#pragma unroll
      for (int r2 = 0; r2 < 4; ++r2)
        pdst[(size_t)(rbase + r2) * 256 + col] = acc[mi][ni][r2];
    }
}

// ---------------- finq: emb_bf = bf16(sum parts + b + pos); q fused ----------------
// grid 256 blocks, 32 rows/block, 8 threads/row (32 cols each).
__global__ __launch_bounds__(256) void finq_kernel(
    const float* __restrict__ part, const float* __restrict__ b_embed,
    const float* __restrict__ pos, const float* __restrict__ WqR,
    unsigned short* __restrict__ emb_bf, float* __restrict__ q) {
  __shared__ float wq[1024];
  const int t = threadIdx.x;
  for (int i = t; i < 1024; i += 256) wq[i] = WqR[i];
  __syncthreads();
  const int row_l = t >> 3, seg = t & 7;
  const int row = blockIdx.x * 32 + row_l;
  const int bn = row >> 10, n = row & 1023;
  const float4* p4 = (const float4*)part;
  const float4* b4 = (const float4*)b_embed;
  const float4* pos4 = (const float4*)pos;
  const float4* wq4 = (const float4*)wq;
  const int idx0 = row * 64 + seg * 8;

  float4 e[8];
#pragma unroll
  for (int j = 0; j < 8; ++j) {
    float4 v = p4[idx0 + j];
    float4 v1 = p4[524288 + idx0 + j];
    float4 v2 = p4[1048576 + idx0 + j];
    float4 v3 = p4[1572864 + idx0 + j];
    float4 bb = b4[seg * 8 + j];
    float4 pp = pos4[(size_t)n * 64 + seg * 8 + j];
    e[j].x = v.x + v1.x + v2.x + v3.x + bb.x + pp.x;
    e[j].y = v.y + v1.y + v2.y + v3.y + bb.y + pp.y;
    e[j].z = v.z + v1.z + v2.z + v3.z + bb.z + pp.z;
    e[j].w = v.w + v1.w + v2.w + v3.w + bb.w + pp.w;
  }
  // bf16 write (32 floats -> 4 uint4)
  unsigned int ub[16];
#pragma unroll
  for (int j = 0; j < 8; ++j) {
    ub[2 * j]     = (unsigned int)f2bf(e[j].x) | ((unsigned int)f2bf(e[j].y) << 16);
    ub[2 * j + 1] = (unsigned int)f2bf(e[j].z) | ((unsigned int)f2bf(e[j].w) << 16);
  }
  uint4* dst = (uint4*)(emb_bf + (size_t)row * 256 + seg * 32);
#pragma unroll
  for (int j = 0; j < 4; ++j)
    dst[j] = make_uint4(ub[4 * j], ub[4 * j + 1], ub[4 * j + 2], ub[4 * j + 3]);
  // q: dot with head-reduced Wq
  float s[4] = {0.f, 0.f, 0.f, 0.f};
#pragma unroll
  for (int h = 0; h < 4; ++h)
#pragma unroll
    for (int j = 0; j < 8; ++j) {
      float4 w = wq4[h * 64 + seg * 8 + j];
      s[h] += e[j].x * w.x + e[j].y * w.y + e[j].z * w.z + e[j].w * w.w;
    }
#pragma unroll
  for (int h = 0; h < 4; ++h) {
    s[h] += __shfl_xor(s[h], 1);
    s[h] += __shfl_xor(s[h], 2);
    s[h] += __shfl_xor(s[h], 4);
  }
  if (seg == 0) {
#pragma unroll
    for (int h = 0; h < 4; ++h)
      q[(size_t)(bn * 4 + h) * 1024 + n] = s[h];
  }
}

// ---------------- kk[bh][m] = sigmoid(q[bh] . Wk[m]) ----------------
// grid 128 (8 m-rows per block), thread = (m = t&7, bh = t>>3).
__global__ __launch_bounds__(256) void k_kernel(const float* __restrict__ q,
                                                const float* __restrict__ Wk,
                                                float* __restrict__ kk) {
  __shared__ float wk_s[8 * KST];
  __shared__ float q_s[32 * KST];
  const int m0 = blockIdx.x * 8;
  const int t = threadIdx.x;
  const int m = t & 7, bh = t >> 3;
  const float4* wkg = (const float4*)Wk;
  const float4* qg = (const float4*)q;
  float acc = 0.f;
  for (int kt = 0; kt < 4; ++kt) {
    const int k0 = kt * 256;
#pragma unroll
    for (int i = 0; i < 2; ++i) {
      int idx = t + i * 256;
      int r = idx >> 6, c4 = idx & 63;
      *(float4*)&wk_s[r * KST + c4 * 4] = wkg[((size_t)(m0 + r) * 1024 + k0) / 4 + c4];
    }
#pragma unroll
    for (int i = 0; i < 8; ++i) {
      int idx = t + i * 256;
      int r = idx >> 6, c4 = idx & 63;
      *(float4*)&q_s[r * KST + c4 * 4] = qg[((size_t)r * 1024 + k0) / 4 + c4];
    }
    __syncthreads();
#pragma unroll 8
    for (int k4 = 0; k4 < 64; ++k4) {
      float4 a = *(const float4*)&wk_s[m * KST + k4 * 4];
      float4 b = *(const float4*)&q_s[bh * KST + k4 * 4];
      acc += a.x * b.x + a.y * b.y + a.z * b.z + a.w * b.w;
    }
    __syncthreads();
  }
  kk[(size_t)bh * 1024 + m0 + m] = 1.f / (1.f + __expf(-acc));
}

// ---------------- vgemm: ov = bf16( (emb_bf @ Wv^T) * gate ) ----------------
// M=8192, N=256, K=256. Tile 32x64, grid (4,256).
__global__ __launch_bounds__(256) void vgemm_kernel(
    const unsigned short* __restrict__ Abf, const unsigned short* __restrict__ Wvb,
    const float* __restrict__ kk, unsigned short* __restrict__ ov) {
  __shared__ __align__(16) unsigned short As[32 * LDA];
  __shared__ __align__(16) unsigned short Bs[64 * LDA];
  const int nt = blockIdx.x, mt = blockIdx.y;
  const int m0 = mt * 32, n0 = nt * 64;
  const int t = threadIdx.x;
  const int wave = t >> 6, lane = t & 63;
  const int wr = wave >> 1, wc = wave & 1;
  const int lr = lane & 15, lq = lane >> 4;
  f32x4 acc[2];
  acc[0] = f32x4{0.f, 0.f, 0.f, 0.f};
  acc[1] = f32x4{0.f, 0.f, 0.f, 0.f};

  for (int kt = 0; kt < 4; ++kt) {
    const int k0 = kt * 64;
    {
      int m = t >> 3, krun = t & 7;
      *(short8*)&As[m * LDA + krun * 8] =
          *(const short8*)(Abf + (size_t)(m0 + m) * 256 + k0 + krun * 8);
    }
#pragma unroll
    for (int rr = 0; rr < 2; ++rr) {
      int r = t + rr * 256;
      int n = r >> 3, krun = r & 7;
      *(short8*)&Bs[n * LDA + krun * 8] =
          *(const short8*)(Wvb + (size_t)(n0 + n) * 256 + k0 + krun * 8);
    }
    __syncthreads();
#pragma unroll
    for (int kc = 0; kc < 2; ++kc) {
      short8 a = *(const short8*)&As[(wr * 16 + lr) * LDA + kc * 32 + lq * 8];
#pragma unroll
      for (int ni = 0; ni < 2; ++ni) {
        short8 b = *(const short8*)&Bs[(wc * 32 + ni * 16 + lr) * LDA + kc * 32 + lq * 8];
        acc[ni] = __builtin_amdgcn_mfma_f32_16x16x32_bf16(a, b, acc[ni], 0, 0, 0);
      }
    }
    __syncthreads();
  }
#pragma unroll
  for (int ni = 0; ni < 2; ++ni) {
    int col = n0 + wc * 32 + ni * 16 + lr;
    int h = col >> 6;
    int rbase = m0 + wr * 16 + lq * 4;
#pragma unroll
    for (int r2 = 0; r2 < 4; ++r2) {
      int row = rbase + r2;
      int bn = row >> 10, n = row & 1023;
      float g = kk[(size_t)(bn * 4 + h) * 1024 + n];
      ov[(size_t)row * 256 + col] = f2bf(acc[ni][r2] * g);
    }
  }
}

// ---------------- GEMM2: out = ov @ Wout^T + b_out, folded, coalesced ----------------
// M=8192, N=4096, K=256. Tile 64x128, grid (32,128). LDS-transposed epilogue.
#define CST 132  // epilogue C_s stride (floats)
__global__ __launch_bounds__(256) void gemm2_out(
    const unsigned short* __restrict__ Abf, const unsigned short* __restrict__ Wob,
    const float* __restrict__ b_out, float* __restrict__ out) {
  __shared__ __align__(16) float smem[64 * CST];  // 33792 B; aliases As/Bs
  unsigned short* As = (unsigned short*)smem;            // 64*72
  unsigned short* Bs = As + 64 * LDA;                    // 128*72
  const int nt = blockIdx.x, mt = blockIdx.y;
  const int m0 = mt * 64, n0 = nt * 128;
  const int t = threadIdx.x;
  const int wave = t >> 6, lane = t & 63;
  const int wm = wave >> 1, wn = wave & 1;
  const int lr = lane & 15, lq = lane >> 4;
  f32x4 acc[2][4];
#pragma unroll
  for (int i = 0; i < 2; i++)
#pragma unroll
    for (int j = 0; j < 4; j++) acc[i][j] = f32x4{0.f, 0.f, 0.f, 0.f};

  for (int kt = 0; kt < 4; ++kt) {
    const int k0 = kt * 64;
#pragma unroll
    for (int rr = 0; rr < 2; ++rr) {
      int r = t + rr * 256;
      int m = r >> 3, krun = r & 7;
      *(short8*)&As[m * LDA + krun * 8] =
          *(const short8*)(Abf + (size_t)(m0 + m) * 256 + k0 + krun * 8);
    }
#pragma unroll
    for (int rr = 0; rr < 4; ++rr) {
      int r = t + rr * 256;
      int n = r >> 3, krun = r & 7;
      *(short8*)&Bs[n * LDA + krun * 8] =
          *(const short8*)(Wob + (size_t)(n0 + n) * 256 + k0 + krun * 8);
    }
    __syncthreads();
#pragma unroll
    for (int kc = 0; kc < 2; ++kc) {
      short8 a0 = *(const short8*)&As[(wm * 32 + lr) * LDA + kc * 32 + lq * 8];
      short8 a1 = *(const short8*)&As[(wm * 32 + 16 + lr) * LDA + kc * 32 + lq * 8];
#pragma unroll
      for (int ni = 0; ni < 4; ++ni) {
        short8 b = *(const short8*)&Bs[(wn * 64 + ni * 16 + lr) * LDA + kc * 32 + lq * 8];
        acc[0][ni] = __builtin_amdgcn_mfma_f32_16x16x32_bf16(a0, b, acc[0][ni], 0, 0, 0);
        acc[1][ni] = __builtin_amdgcn_mfma_f32_16x16x32_bf16(a1, b, acc[1][ni], 0, 0, 0);
      }
    }
    __syncthreads();
  }
  // stage C tile into LDS [m_local][p_local]
#pragma unroll
  for (int mi = 0; mi < 2; ++mi)
#pragma unroll
    for (int ni = 0; ni < 4; ++ni) {
      int pl = wn * 64 + ni * 16 + lr;
      int mb = wm * 32 + mi * 16 + lq * 4;
#pragma unroll
      for (int r2 = 0; r2 < 4; ++r2)
        smem[(mb + r2) * CST + pl] = acc[mi][ni][r2];
    }
  __syncthreads();
  // coalesced folded write: tile = 2 contiguous 16 KiB runs (one per c2)
  const int bn = m0 >> 10;
  const int ph0 = (m0 & 1023) >> 5;
  const int c0 = n0 >> 6;
#pragma unroll
  for (int i = 0; i < 8; ++i) {
    int idx4 = t + i * 256;                  // 0..2047 float4s
    int kw4 = idx4 & 1;
    int pw = (idx4 >> 1) & 31;
    int kh = (idx4 >> 6) & 7;
    int c2 = (idx4 >> 9) & 1;
    int ph = (idx4 >> 10) & 1;
    int m_local = ph * 32 + pw;
    int p_local = c2 * 64 + kh * 8 + kw4 * 4;
    float4 v = *(const float4*)&smem[m_local * CST + p_local];
    float4 bo = *(const float4*)(b_out + n0 + p_local);
    v.x += bo.x; v.y += bo.y; v.z += bo.z; v.w += bo.w;
    size_t addr = ((size_t)((bn << 6) + c0 + c2) << 16) +
                  (size_t)(((ph0 + ph) << 3) + kh) * 256 + (pw << 3) + kw4 * 4;
    *(float4*)(out + addr) = v;
  }
}

extern "C" void kernel_launch(void* const* d_in, const int* in_sizes, int n_in,
                              void* d_out, int out_size, void* d_ws, size_t ws_size,
                              hipStream_t stream) {
  const float* x       = (const float*)d_in[0];
  const float* W_embed = (const float*)d_in[1];
  const float* b_embed = (const float*)d_in[2];
  const float* pos     = (const float*)d_in[3];
  const float* Wq      = (const float*)d_in[4];
  const float* Wk      = (const float*)d_in[5];
  const float* Wv      = (const float*)d_in[6];
  const float* Wout    = (const float*)d_in[7];
  const float* b_out   = (const float*)d_in[8];
  float* out = (float*)d_out;

  char* ws = (char*)d_ws;
  const size_t MB = 1024 * 1024;
  float* part            = (float*)(ws);                      // 32 MiB (4 x 8 MiB)
  unsigned short* ov     = (unsigned short*)(ws);             // 4 MiB, aliases part (dead by then)
  unsigned short* emb_bf = (unsigned short*)(ws + 32 * MB);   // 4 MiB
  unsigned short* Wb     = (unsigned short*)(ws + 36 * MB);   // 2 MiB
  unsigned short* Wob    = (unsigned short*)(ws + 38 * MB);   // 2 MiB
  unsigned short* Wvb    = (unsigned short*)(ws + 40 * MB);   // 128 KiB
  float* q               = (float*)(ws + 40 * MB + 131072);   // 128 KiB
  float* kk              = (float*)(ws + 40 * MB + 262144);   // 128 KiB
  float* WqR             = (float*)(ws + 40 * MB + 393216);   // 4 KiB

  prep_kernel<<<2116, 256, 0, stream>>>(W_embed, Wout, Wv, Wq, Wb, Wob, Wvb, WqR);
  gemm1_embed<<<dim3(2, 128, 4), 256, 0, stream>>>(x, Wb, part);
  finq_kernel<<<256, 256, 0, stream>>>(part, b_embed, pos, WqR, emb_bf, q);
  k_kernel<<<128, 256, 0, stream>>>(q, Wk, kk);
  vgemm_kernel<<<dim3(4, 256), 256, 0, stream>>>(emb_bf, Wvb, kk, ov);
  gemm2_out<<<dim3(32, 128), 256, 0, stream>>>(ov, Wob, b_out, out);
}